// Round 16
// baseline (591.978 us; speedup 1.0000x reference)
//
#include <hip/hip_runtime.h>
#include <cstdint>
#include <cstddef>

// ---------------- types ----------------
typedef __attribute__((ext_vector_type(8))) _Float16 half8;   // MFMA f16 A/B frag (4 VGPRs)
typedef __attribute__((ext_vector_type(4))) _Float16 half4;
typedef __attribute__((ext_vector_type(2))) __fp16   fp16x2;  // cvt_pkrtz result type
typedef __attribute__((ext_vector_type(4))) float    floatx4; // MFMA C/D frag

static constexpr int B_ROWS = 16384;
static constexpr int IN_DIM = 256;
static constexpr int H_DIM  = 512;
static constexpr int NB     = 16;
static constexpr int NBLK   = 512;   // 2 blocks/CU x 256 CU, co-resident (proven: R13 ran to completion)

__device__ __forceinline__ float fast_tanh(float x) {
  float ax = fabsf(x);
  float e  = __expf(2.0f * ax);             // e >= 1, inf-safe
  float t  = 1.0f - 2.0f / (e + 1.0f);
  return copysignf(t, x);
}

// async global->LDS, 16B per lane; LDS dest must be wave-uniform base + lane*16
__device__ __forceinline__ void gld16(const void* g, void* l) {
  __builtin_amdgcn_global_load_lds(
      (const __attribute__((address_space(1))) unsigned int*)g,
      (__attribute__((address_space(3))) unsigned int*)l, 16, 0, 0);
}

// device-scope (coherent-point) relaxed stores/loads: write-through sc1, no L2-dirty
// state, no fences. Validated in-kernel by R15 (bit-exact handoff psum->stats).
__device__ __forceinline__ void dev_store(float* p, float v) {
  __hip_atomic_store(p, v, __ATOMIC_RELAXED, __HIP_MEMORY_SCOPE_AGENT);
}
__device__ __forceinline__ float dev_load(const float* p) {
  return __hip_atomic_load(p, __ATOMIC_RELAXED, __HIP_MEMORY_SCOPE_AGENT);
}
__device__ __forceinline__ void dev_store8(void* p, unsigned long long v) {
  __hip_atomic_store((unsigned long long*)p, v, __ATOMIC_RELAXED, __HIP_MEMORY_SCOPE_AGENT);
}

// ---------------- grid barrier v2: NO acquire, NO release, NO threadfence ----------------
// R13's disaster was acquire-in-spin (every poll = per-XCD L2 invalidate). Here:
// __syncthreads drains vmcnt (sc1 stores ack'd at coherent point), relaxed arrive,
// relaxed spin (LLC reads, no cache maintenance). Cross-phase visibility comes from
// sc1 write-through stores + first-touch reads (distinct buffers per phase edge).
__device__ __forceinline__ void grid_barrier(unsigned* bar, int idx) {
  __syncthreads();
  if (threadIdx.x == 0) {
    __hip_atomic_fetch_add(&bar[idx], 1u, __ATOMIC_RELAXED, __HIP_MEMORY_SCOPE_AGENT);
    while (__hip_atomic_load(&bar[idx], __ATOMIC_RELAXED, __HIP_MEMORY_SCOPE_AGENT)
           < (unsigned)NBLK) {
      __builtin_amdgcn_s_sleep(8);
    }
  }
  __syncthreads();
}

// ---------------- distributed column stats: block b computes column b ----------------
// Serial f64 sum over segs ascending (bit-matches stats_final_k lineage; R13-proven).
__device__ __forceinline__ void col_stats(const float* ps, const float* ps2,
                                          int segs, int C, float2* snpk,
                                          int b, int tid, double* Lred) {
  if (b < C) {
    double s = 0.0, s2 = 0.0;
    if (tid < segs) {
      s  = ps [(size_t)tid * C + b];
      s2 = ps2[(size_t)tid * C + b];
    }
    Lred[tid] = s;
    Lred[512 + tid] = s2;
    __syncthreads();
    if (tid == 0) {
      double S = 0.0, S2 = 0.0;
      for (int g = 0; g < segs; g++) { S += Lred[g]; S2 += Lred[512 + g]; }
      double mean = S / B_ROWS;
      double var  = (S2 - S * S / B_ROWS) / (B_ROWS - 1);   // ddof=1
      if (var < 0.0) var = 0.0;
      float iv = 1.0f / ((float)sqrt(var) + 1e-6f);
      union { float2 f; unsigned long long u; } cv;
      cv.f = make_float2(iv, -(float)mean * iv);
      dev_store8(&snpk[b], cv.u);
    }
    __syncthreads();
  } else {
    __syncthreads();   // keep block-barrier parity with b<C blocks
    __syncthreads();
  }
}

// ---------------- GEMM phase: R10/R15 loop verbatim ----------------
// 128x128 tile, BK=64, 8 waves = 2m x 2n x 2k (k-split), role-ordered (ksw=1
// expand-first), DMA tri-buffer + counted vmcnt (never drained in-loop), erow=tid&127
// A-write banking (conflicts=0), packed f16 expansion, lgkm-only raw barriers,
// LDS k-split merge. Cross-phase outputs (Hout, psum) via dev_store (sc1).
__device__ void gemm_phase(const float* __restrict__ X, const float2* __restrict__ snpk,
                           const _Float16* __restrict__ Bm, float* __restrict__ Hout,
                           float* __restrict__ psum, float* __restrict__ psum2,
                           int C, unsigned char* LDSB, int bblk) {
  const int K = C << 4;
  const int steps = K >> 6;                 // BK = 64
  _Float16* const Asb = reinterpret_cast<_Float16*>(LDSB);           // 2 x 8192 halfs
  _Float16* const Bsb = reinterpret_cast<_Float16*>(LDSB + 32768);   // 3 x 8192 halfs
  const int tid  = threadIdx.x;
  const int w = tid >> 6, lane = tid & 63;
  const int wm = w & 1, wn = (w >> 1) & 1, ksw = w >> 2;
  const int lrow = lane & 15, quad = lane >> 4;
  const int row0 = (bblk & 127) * 128;
  const int col0 = (bblk >> 7) * 128;
  const int kq = ksw * 4 + quad;

  const int s_row = tid >> 3;
  const int s_sl  = tid & 7;
  const int s_seg = s_sl ^ ((s_row >> 1) & 7);
  const _Float16* gB = Bm + (size_t)(col0 + s_row) * K + s_seg * 8;

  const int erow = tid & 127;
  const int eh   = tid >> 7;
  const float*  xp  = X    + (size_t)(row0 + erow) * C + eh;
  const float2* snp = snpk + eh;

  floatx4 acc[4][4] = {};

  auto expand_store = [&](float xr, float2 sn, int bufi) {
    float xn = fminf(fmaxf(fmaf(xr, sn.x, sn.y), -3.f), 3.f);
    float Wv = __expf(fmaf(-2.f, xn, -8.f) * xn);
    float g  = __expf((16.f / 15.f) * xn);
    float g2 = g * g, g4 = g2 * g2, g8 = g4 * g4;
    fp16x2 gg = __builtin_amdgcn_cvt_pkrtz(g2, g2);
    union { fp16x2 q[4]; half8 v8; } u0, u1;
    u0.q[0] = __builtin_amdgcn_cvt_pkrtz(Wv, Wv * g);
    u0.q[1] = u0.q[0] * gg;
    u0.q[2] = u0.q[1] * gg;
    u0.q[3] = u0.q[2] * gg;
    float W8 = Wv * g8;
    u1.q[0] = __builtin_amdgcn_cvt_pkrtz(W8, W8 * g);
    u1.q[1] = u1.q[0] * gg;
    u1.q[2] = u1.q[1] * gg;
    u1.q[3] = u1.q[2] * gg;
    int ks0 = 2 * eh;
    *(half8*)&Asb[(size_t)bufi * 8192 + (size_t)(ks0 * 128 + erow) * 8]       = u0.v8;
    *(half8*)&Asb[(size_t)bufi * 8192 + (size_t)((ks0 + 1) * 128 + erow) * 8] = u1.v8;
  };

  // ---- prologue: DMA(0), DMA(1), expand(0); one-time vmcnt(0) drain ----
  float  x0  = xp[0];
  float2 sn0 = snp[0];
  gld16(gB, &Bsb[(size_t)tid * 8]);
  gld16(gB + (size_t)64 * K, &Bsb[(size_t)(tid + 512) * 8]);
  __builtin_amdgcn_sched_barrier(0);
  gld16(gB + 64, &Bsb[8192 + (size_t)tid * 8]);
  gld16(gB + 64 + (size_t)64 * K, &Bsb[8192 + (size_t)(tid + 512) * 8]);
  __builtin_amdgcn_sched_barrier(0);
  float  xv = xp[4];
  float2 sv = snp[4];
  expand_store(x0, sn0, 0);
  asm volatile("s_waitcnt vmcnt(0)" ::: "memory");
  asm volatile("s_waitcnt lgkmcnt(0)" ::: "memory");
  __builtin_amdgcn_s_barrier();
  __builtin_amdgcn_sched_barrier(0);

  // ---- main loop: raw barrier per step, vmcnt never drained; role-ordered by ksw ----
  int bcur = 0;
  for (int k = 0; k < steps; k++) {
    const int abuf = k & 1;
    const bool more  = (k + 1 < steps);
    const bool more2 = (k + 2 < steps);
    const int b2 = (bcur == 0) ? 2 : bcur - 1;
    if (more2) {
      gld16(gB + (size_t)(k + 2) * 64, &Bsb[(size_t)b2 * 8192 + (size_t)tid * 8]);
      gld16(gB + (size_t)(k + 2) * 64 + (size_t)64 * K,
            &Bsb[(size_t)b2 * 8192 + (size_t)(tid + 512) * 8]);
      __builtin_amdgcn_sched_barrier(0);
    }
    half8 af[4], bf[4];
    auto read_frags = [&]() {
#pragma unroll
      for (int t = 0; t < 4; t++) {
        int arow = wm * 64 + t * 16 + lrow;
        af[t] = *(const half8*)&Asb[(size_t)abuf * 8192 + (size_t)(kq * 128 + arow) * 8];
      }
#pragma unroll
      for (int t = 0; t < 4; t++) {
        int brow = wn * 64 + t * 16 + lrow;
        int bchunk = brow * 8 + (kq ^ ((brow >> 1) & 7));
        bf[t] = *(const half8*)&Bsb[(size_t)bcur * 8192 + (size_t)bchunk * 8];
      }
    };
    auto do_expand = [&]() {
      if (more) {
        expand_store(xv, sv, abuf ^ 1);
        if (more2) {
          xv = xp[4 * (k + 2)];
          sv = snp[4 * (k + 2)];
        }
      }
    };
    if (ksw == 0) {
      read_frags();
      __builtin_amdgcn_s_setprio(1);
#pragma unroll
      for (int tm = 0; tm < 2; tm++)
#pragma unroll
        for (int tn = 0; tn < 4; tn++)
          acc[tm][tn] = __builtin_amdgcn_mfma_f32_16x16x32_f16(af[tm], bf[tn], acc[tm][tn], 0, 0, 0);
      __builtin_amdgcn_s_setprio(0);
      do_expand();
      __builtin_amdgcn_s_setprio(1);
#pragma unroll
      for (int tm = 2; tm < 4; tm++)
#pragma unroll
        for (int tn = 0; tn < 4; tn++)
          acc[tm][tn] = __builtin_amdgcn_mfma_f32_16x16x32_f16(af[tm], bf[tn], acc[tm][tn], 0, 0, 0);
      __builtin_amdgcn_s_setprio(0);
    } else {
      do_expand();
      read_frags();
      __builtin_amdgcn_s_setprio(1);
#pragma unroll
      for (int tm = 0; tm < 4; tm++)
#pragma unroll
        for (int tn = 0; tn < 4; tn++)
          acc[tm][tn] = __builtin_amdgcn_mfma_f32_16x16x32_f16(af[tm], bf[tn], acc[tm][tn], 0, 0, 0);
      __builtin_amdgcn_s_setprio(0);
    }
    asm volatile("s_waitcnt lgkmcnt(0)" ::: "memory");
    __builtin_amdgcn_s_barrier();
    __builtin_amdgcn_sched_barrier(0);
    bcur = (bcur == 2) ? 0 : bcur + 1;
  }

  // ---- k-split merge ----
  float* MB = reinterpret_cast<float*>(LDSB);
  const int p = wm * 2 + wn;
  asm volatile("s_waitcnt vmcnt(0)" ::: "memory");
  if (ksw == 1) {
    float* dst = MB + (size_t)p * 4096;
#pragma unroll
    for (int tm = 0; tm < 4; tm++)
#pragma unroll
      for (int tn = 0; tn < 4; tn++)
        *(floatx4*)&dst[((tm * 4 + tn) * 64 + lane) * 4] = acc[tm][tn];
  }
  asm volatile("s_waitcnt lgkmcnt(0)" ::: "memory");
  __builtin_amdgcn_s_barrier();
  __builtin_amdgcn_sched_barrier(0);

  float* Rs1 = MB + 16384;
  float* Rs2 = Rs1 + 256;
  if (ksw == 0) {
    const float* src = MB + (size_t)p * 4096;
    float s1[4] = {0.f, 0.f, 0.f, 0.f}, s2v[4] = {0.f, 0.f, 0.f, 0.f};
#pragma unroll
    for (int tm = 0; tm < 4; tm++) {
#pragma unroll
      for (int tn = 0; tn < 4; tn++) {
        floatx4 other = *(const floatx4*)&src[((tm * 4 + tn) * 64 + lane) * 4];
        int gcol = col0 + wn * 64 + tn * 16 + lrow;
#pragma unroll
        for (int r = 0; r < 4; r++) {
          int grow = row0 + wm * 64 + tm * 16 + quad * 4 + r;
          float v = fast_tanh(acc[tm][tn][r] + other[r]);
          dev_store(&Hout[(size_t)grow * H_DIM + gcol], v);
          s1[tn] += v; s2v[tn] += v * v;
        }
      }
    }
#pragma unroll
    for (int tn = 0; tn < 4; tn++) {
      s1[tn]  += __shfl_xor(s1[tn], 16);  s1[tn]  += __shfl_xor(s1[tn], 32);
      s2v[tn] += __shfl_xor(s2v[tn], 16); s2v[tn] += __shfl_xor(s2v[tn], 32);
    }
    if (quad == 0) {
#pragma unroll
      for (int tn = 0; tn < 4; tn++) {
        Rs1[wm * 128 + wn * 64 + tn * 16 + lrow] = s1[tn];
        Rs2[wm * 128 + wn * 64 + tn * 16 + lrow] = s2v[tn];
      }
    }
  }
  asm volatile("s_waitcnt lgkmcnt(0)" ::: "memory");
  __builtin_amdgcn_s_barrier();
  __builtin_amdgcn_sched_barrier(0);
  if (tid < 128) {
    dev_store(&psum [(size_t)(bblk & 127) * H_DIM + col0 + tid], Rs1[tid] + Rs1[128 + tid]);
    dev_store(&psum2[(size_t)(bblk & 127) * H_DIM + col0 + tid], Rs2[tid] + Rs2[128 + tid]);
  }
}

// ---------------- the whole network in ONE persistent kernel ----------------
// R22 = R13's phase structure + the two fixes: (1) relaxed-spin barrier (R13's
// acquire-in-spin = continuous per-XCD L2 invalidates = 3x phase slowdown);
// (2) sc1 write-through for ALL cross-phase data + DISTINCT buffers per phase edge
// (first-touch reads -> no stale lines, no acquire needed anywhere).
__global__ __launch_bounds__(512, 4) void kan_all(
    const float* __restrict__ X,  const float* __restrict__ c1,
    const float* __restrict__ c2, const float* __restrict__ c3,
    const float* __restrict__ SW, const float* __restrict__ SB,
    _Float16* __restrict__ C1h, _Float16* __restrict__ C2h,
    float* __restrict__ H1, float* __restrict__ H2,
    float* __restrict__ psX, float* __restrict__ ps2X,
    float* __restrict__ psA, float* __restrict__ ps2A,
    float* __restrict__ psB, float* __restrict__ ps2B,
    float2* __restrict__ snpkX, float2* __restrict__ snpkA, float2* __restrict__ snpkB,
    unsigned* __restrict__ bar,
    float* __restrict__ OUT) {
  __shared__ __align__(16) unsigned char LDSB[81920];
  const int tid = threadIdx.x;
  const int b   = blockIdx.x;
  double* Lred = reinterpret_cast<double*>(LDSB);   // 1024 doubles = 8 KB (stats scratch)

  // ======== phase 0: x column-stats partials + coeff cvt ========
  {
    float* Ls  = reinterpret_cast<float*>(LDSB);
    float* Ls2 = Ls + 512;
    int lane6 = tid & 63, chunk = tid >> 6;         // 8 chunks
    int c  = (b & 3) * 64 + lane6;
    int sg = b >> 2;                                // 128 segs x 128 rows
    int r0 = sg * 128;
    double s = 0.0, s2 = 0.0;
    for (int r = r0 + chunk; r < r0 + 128; r += 8) {
      float v = X[(size_t)r * IN_DIM + c];
      s += v; s2 += (double)v * (double)v;
    }
    Ls[tid] = (float)s; Ls2[tid] = (float)s2;
    __syncthreads();
    if (chunk == 0) {
      float a = 0.f, bb = 0.f;
#pragma unroll
      for (int ch = 0; ch < 8; ch++) { a += Ls[lane6 + 64 * ch]; bb += Ls2[lane6 + 64 * ch]; }
      dev_store(&psX [(size_t)sg * IN_DIM + c], a);
      dev_store(&ps2X[(size_t)sg * IN_DIM + c], bb);
    }
    // coeff cvt (elementwise); fp16 outputs stored sc1 (8B) for first-touch readers
    size_t n41 = (size_t)H_DIM * IN_DIM * NB / 4;
    size_t n42 = (size_t)H_DIM * H_DIM * NB / 4;
    size_t tot = n41 + n42;
    for (size_t i = (size_t)b * 512 + tid; i < tot; i += (size_t)NBLK * 512) {
      const float4* sp; half4* dp; size_t j;
      if (i < n41) { sp = (const float4*)c1; dp = (half4*)C1h; j = i; }
      else         { sp = (const float4*)c2; dp = (half4*)C2h; j = i - n41; }
      float4 v = sp[j];
      int nb = (int)((j << 2) & 15);
      union { half4 h; unsigned long long u; } r;
      float e0 = -2.f + (float)(nb + 0) * (4.f / 15.f);
      float e1 = -2.f + (float)(nb + 1) * (4.f / 15.f);
      float e2 = -2.f + (float)(nb + 2) * (4.f / 15.f);
      float e3 = -2.f + (float)(nb + 3) * (4.f / 15.f);
      r.h[0] = (_Float16)(v.x * __expf(-2.f * e0 * e0));
      r.h[1] = (_Float16)(v.y * __expf(-2.f * e1 * e1));
      r.h[2] = (_Float16)(v.z * __expf(-2.f * e2 * e2));
      r.h[3] = (_Float16)(v.w * __expf(-2.f * e3 * e3));
      dev_store8(&dp[j], r.u);
    }
  }
  grid_barrier(bar, 0);

  // ======== phase 1: x stats finalize (block b -> col b) ========
  col_stats(psX, ps2X, 128, IN_DIM, snpkX, b, tid, Lred);
  grid_barrier(bar, 1);

  // ======== phase 2: layer 1 GEMM ========
  gemm_phase(X, snpkX, C1h, H1, psA, ps2A, IN_DIM, LDSB, b);
  grid_barrier(bar, 2);

  // ======== phase 3: H1 stats finalize ========
  col_stats(psA, ps2A, 128, H_DIM, snpkA, b, tid, Lred);
  grid_barrier(bar, 3);

  // ======== phase 4: layer 2 GEMM ========
  gemm_phase(H1, snpkA, C2h, H2, psB, ps2B, H_DIM, LDSB, b);
  grid_barrier(bar, 4);

  // ======== phase 5: H2 stats finalize ========
  col_stats(psB, ps2B, 128, H_DIM, snpkB, b, tid, Lred);
  grid_barrier(bar, 5);

  // ======== phase 6: layer 3 + skip ========
  {
    int w = tid >> 6, lane = tid & 63;
    float Kn[NB];
#pragma unroll
    for (int n = 0; n < NB; n++) {
      float c = -2.f + (float)n * (4.f / 15.f);
      Kn[n] = __expf(-2.f * c * c);
    }
    float sb0 = SB[0];
    int row_base = b * 32 + w * 4;                  // 512 blocks x 8 waves x 4 rows
    for (int r = 0; r < 4; r++) {
      int row = row_base + r;
      float s = 0.f;
#pragma unroll
      for (int j = 0; j < 8; j++) {
        int i = lane + 64 * j;
        float hv = H2[(size_t)row * H_DIM + i];
        float2 sn = snpkB[i];
        float xn = fminf(fmaxf(fmaf(hv, sn.x, sn.y), -3.f), 3.f);
        float Wf = __expf(fmaf(-2.f, xn, -8.f) * xn);
        float gf = __expf((16.f / 15.f) * xn);
        const floatx4* cp = (const floatx4*)(c3 + (size_t)i * NB);
        floatx4 c0 = cp[0], c1v = cp[1], c2v = cp[2], c3v = cp[3];
        float p = Wf;
#pragma unroll
        for (int n = 0; n < 4; n++) { s += p * Kn[n]      * c0[n];  p *= gf; }
#pragma unroll
        for (int n = 0; n < 4; n++) { s += p * Kn[n + 4]  * c1v[n]; p *= gf; }
#pragma unroll
        for (int n = 0; n < 4; n++) { s += p * Kn[n + 8]  * c2v[n]; p *= gf; }
#pragma unroll
        for (int n = 0; n < 4; n++) { s += p * Kn[n + 12] * c3v[n]; p *= gf; }
      }
#pragma unroll
      for (int j = 0; j < 4; j++) {
        int i = lane + 64 * j;
        s += X[(size_t)row * IN_DIM + i] * SW[i];
      }
#pragma unroll
      for (int off = 32; off > 0; off >>= 1) s += __shfl_down(s, off);
      if (lane == 0) OUT[row] = s + sb0;           // plain store: dispatch-end writeback
    }
  }
}

// ---------------- launcher ----------------
extern "C" void kernel_launch(void* const* d_in, const int* in_sizes, int n_in,
                              void* d_out, int out_size, void* d_ws, size_t ws_size,
                              hipStream_t stream) {
  const float* x  = (const float*)d_in[0];   // [16384, 256]
  const float* c1 = (const float*)d_in[1];   // [512, 256, 16]
  const float* c2 = (const float*)d_in[2];   // [512, 512, 16]
  const float* c3 = (const float*)d_in[3];   // [1, 512, 16]
  const float* sw = (const float*)d_in[4];   // [1, 256]
  const float* sb = (const float*)d_in[5];   // [1]
  float* out = (float*)d_out;

  const int B = B_ROWS, IN = IN_DIM, H = H_DIM;

  char* ws = (char*)d_ws;
  size_t off = 0;
  auto alloc = [&](size_t bytes) -> void* {
    void* p = ws + off;
    off += (bytes + 255) & ~(size_t)255;
    return p;
  };
  unsigned* bar = (unsigned*)alloc(256);                      // 6 barrier counters
  _Float16* C1h = (_Float16*)alloc((size_t)H * IN * NB * 2);  //  4 MB
  _Float16* C2h = (_Float16*)alloc((size_t)H * H  * NB * 2);  //  8 MB
  float* H1 = (float*)alloc((size_t)B * H * 4);               // 32 MB
  float* H2 = (float*)alloc((size_t)B * H * 4);               // 32 MB
  // distinct buffers per phase edge: every cross-phase read is FIRST-TOUCH
  float* psX  = (float*)alloc(128 * 256 * 4);
  float* ps2X = (float*)alloc(128 * 256 * 4);
  float* psA  = (float*)alloc(128 * 512 * 4);
  float* ps2A = (float*)alloc(128 * 512 * 4);
  float* psB  = (float*)alloc(128 * 512 * 4);
  float* ps2B = (float*)alloc(128 * 512 * 4);
  float2* snpkX = (float2*)alloc(512 * 8);
  float2* snpkA = (float2*)alloc(512 * 8);
  float2* snpkB = (float2*)alloc(512 * 8);

  // zero barrier counters (stream-ordered, graph-capturable)
  hipMemsetAsync(bar, 0, 256, stream);

  kan_all<<<NBLK, 512, 0, stream>>>(x, c1, c2, c3, sw, sb,
                                    C1h, C2h, H1, H2,
                                    psX, ps2X, psA, ps2A, psB, ps2B,
                                    snpkX, snpkA, snpkB, bar, out);
}

// Round 17
// 438.325 us; speedup vs baseline: 1.3505x; 1.3505x over previous
//
#include <hip/hip_runtime.h>
#include <cstdint>
#include <cstddef>

// ---------------- types ----------------
typedef __attribute__((ext_vector_type(8)))  _Float16 half8;   // MFMA f16 A/B frag (4 VGPRs)
typedef __attribute__((ext_vector_type(4)))  _Float16 half4;
typedef __attribute__((ext_vector_type(2)))  __fp16   fp16x2;  // cvt_pkrtz result type
typedef __attribute__((ext_vector_type(4)))  float    floatx4;
typedef __attribute__((ext_vector_type(16))) float    floatx16; // 32x32 MFMA C/D frag

static constexpr int B_ROWS = 16384;
static constexpr int IN_DIM = 256;
static constexpr int H_DIM  = 512;
static constexpr int NB     = 16;

__device__ __forceinline__ float fast_tanh(float x) {
  float ax = fabsf(x);
  float e  = __expf(2.0f * ax);             // e >= 1, inf-safe
  float t  = 1.0f - 2.0f / (e + 1.0f);
  return copysignf(t, x);
}

// async global->LDS, 16B per lane; LDS dest must be wave-uniform base + lane*16
__device__ __forceinline__ void gld16(const void* g, void* l) {
  __builtin_amdgcn_global_load_lds(
      (const __attribute__((address_space(1))) unsigned int*)g,
      (__attribute__((address_space(3))) unsigned int*)l, 16, 0, 0);
}

// device-scope (coherent-point) relaxed store/load (R15-validated for SMALL handoff
// data only — partials/snpk; bulk data uses plain cached stores).
__device__ __forceinline__ void dev_store(float* p, float v) {
  __hip_atomic_store(p, v, __ATOMIC_RELAXED, __HIP_MEMORY_SCOPE_AGENT);
}
__device__ __forceinline__ float dev_load(const float* p) {
  return __hip_atomic_load(p, __ATOMIC_RELAXED, __HIP_MEMORY_SCOPE_AGENT);
}

// ---------------- prep: x column-stats partials + coeff cvt + last-block x-stats finalize ----
// R15 tail: sc1-store partials + RELAXED arrive (no wbl2) + last-block finalize.
__global__ __launch_bounds__(256) void prep_k(const float* __restrict__ c1, _Float16* __restrict__ d1, size_t n41,
                                              const float* __restrict__ c2, _Float16* __restrict__ d2, size_t n42,
                                              const float* __restrict__ X,
                                              float* __restrict__ ps, float* __restrict__ ps2,
                                              unsigned* __restrict__ cnt,
                                              float2* __restrict__ snpk) {
  const int bx = blockIdx.x;
  __shared__ float Ls[256], Ls2[256];
  __shared__ int lastf;
  if (bx < 128) {
    int c     = (bx & 3) * 64 + (threadIdx.x & 63);
    int chunk = threadIdx.x >> 6;
    int seg   = bx >> 2;
    int r0    = seg * 512;
    double s = 0.0, s2 = 0.0;
    for (int r = r0 + chunk; r < r0 + 512; r += 4) {
      float v = X[(size_t)r * IN_DIM + c];
      s += v; s2 += (double)v * (double)v;
    }
    Ls[threadIdx.x] = (float)s; Ls2[threadIdx.x] = (float)s2;
    __syncthreads();
    if (chunk == 0) {
      int cl = threadIdx.x;
      float a  = Ls[cl]  + Ls[cl + 64]  + Ls[cl + 128]  + Ls[cl + 192];
      float b  = Ls2[cl] + Ls2[cl + 64] + Ls2[cl + 128] + Ls2[cl + 192];
      dev_store(&ps [(size_t)seg * IN_DIM + c], a);
      dev_store(&ps2[(size_t)seg * IN_DIM + c], b);
    }
  } else {
    size_t tot = n41 + n42;
    int nb_blocks = gridDim.x - 128;
    for (size_t i = (size_t)(bx - 128) * 256 + threadIdx.x; i < tot;
         i += (size_t)nb_blocks * 256) {
      const float4* sp; half4* dp; size_t j;
      if (i < n41) { sp = (const float4*)c1; dp = (half4*)d1; j = i; }
      else         { sp = (const float4*)c2; dp = (half4*)d2; j = i - n41; }
      float4 v = sp[j];
      int nb = (int)((j << 2) & 15);
      half4 r;
      float e0 = -2.f + (float)(nb + 0) * (4.f / 15.f);
      float e1 = -2.f + (float)(nb + 1) * (4.f / 15.f);
      float e2 = -2.f + (float)(nb + 2) * (4.f / 15.f);
      float e3 = -2.f + (float)(nb + 3) * (4.f / 15.f);
      r[0] = (_Float16)(v.x * __expf(-2.f * e0 * e0));
      r[1] = (_Float16)(v.y * __expf(-2.f * e1 * e1));
      r[2] = (_Float16)(v.z * __expf(-2.f * e2 * e2));
      r[3] = (_Float16)(v.w * __expf(-2.f * e3 * e3));
      dp[j] = r;
    }
  }
  __syncthreads();
  if (threadIdx.x == 0) {
    unsigned old = __hip_atomic_fetch_add(cnt, 1u, __ATOMIC_RELAXED, __HIP_MEMORY_SCOPE_AGENT);
    lastf = (old == gridDim.x - 1) ? 1 : 0;
  }
  __syncthreads();
  if (lastf) {
    int c = threadIdx.x;
    double s = 0.0, s2 = 0.0;
    for (int g = 0; g < 32; g++) {
      s  += dev_load(&ps [(size_t)g * IN_DIM + c]);
      s2 += dev_load(&ps2[(size_t)g * IN_DIM + c]);
    }
    double mean = s / B_ROWS;
    double var  = (s2 - s * s / B_ROWS) / (B_ROWS - 1);   // ddof=1
    if (var < 0.0) var = 0.0;
    float iv = 1.0f / ((float)sqrt(var) + 1e-6f);
    snpk[c] = make_float2(iv, -(float)mean * iv);
  }
}

// ---------------- fused normalize+expand+GEMM+tanh + col-partials + last-block stats ----
// R23: 16x16x32 -> 32x32x16 MFMA. Serial-pipe budget (R9/R10): step 2944 cyc =
// MFMA 1242 + VALU 1190 + LDS 600. 32x32x16 is ~8.07 cyc per 32768 FLOP vs 4.85 per
// 16384 -> -17% MFMA-pipe cycles, -50% issue slots, SAME LDS bytes. Wave tile stays
// 64x64 over half-BK: acc = 2x2 f32x16; frags af/bf[kc][.], k-group = lane>>5
// (direct analog of the working quad selector); A-read conflict-free (consecutive
// rows); B-read swizzle spreads over 8 bank-groups. C/D: col=lane&31,
// row=(r&3)+8*(r>>2)+4*(lane>>5) (HW-verified mapping). All else R15-verbatim:
// staging swizzle, DMA tri-buffer + counted vmcnt (never drained in-loop),
// role-ordered wave groups, erow A-write banking, packed f16 expansion, lgkm-only
// raw barriers, LDS k-split merge (re-indexed), relaxed-arrive stats tail.
__global__ __launch_bounds__(512, 4) void kan_gemm_fused(const float* __restrict__ X,   // [B, C]
                                                         const float2* __restrict__ snpk, // [C] in
                                                         const _Float16* __restrict__ Bm, // [512, C*16]
                                                         float* __restrict__ Hout,        // [B, 512]
                                                         float* __restrict__ psum,        // [128, 512]
                                                         float* __restrict__ psum2,       // [128, 512]
                                                         int C,
                                                         unsigned* __restrict__ cnt,
                                                         float2* __restrict__ snpk_out) { // [512] out (distinct)
  const int K = C << 4;
  const int steps = K >> 6;                 // BK = 64
  __shared__ __align__(16) unsigned char LDSB[81920];
  _Float16* const Asb = reinterpret_cast<_Float16*>(LDSB);           // 2 x 8192 halfs
  _Float16* const Bsb = reinterpret_cast<_Float16*>(LDSB + 32768);   // 3 x 8192 halfs
  const int tid  = threadIdx.x;
  const int w = tid >> 6, lane = tid & 63;
  const int wm = w & 1, wn = (w >> 1) & 1, ksw = w >> 2;  // 2x2 spatial, 2-way k-split
  const int lane31 = lane & 31, khalf = lane >> 5;
  const int row0 = blockIdx.x * 128;
  const int col0 = blockIdx.y * 128;

  const int s_row = tid >> 3;               // 0..63
  const int s_sl  = tid & 7;
  const int s_seg = s_sl ^ ((s_row >> 1) & 7);
  const _Float16* gB = Bm + (size_t)(col0 + s_row) * K + s_seg * 8;

  const int erow = tid & 127;
  const int eh   = tid >> 7;
  const float*  xp  = X    + (size_t)(row0 + erow) * C + eh;  // step k: xp[4k]
  const float2* snp = snpk + eh;                              // step k: snp[4k]

  floatx16 acc[2][2] = {};

  auto expand_store = [&](float xr, float2 sn, int bufi) {
    float xn = fminf(fmaxf(fmaf(xr, sn.x, sn.y), -3.f), 3.f);
    float Wv = __expf(fmaf(-2.f, xn, -8.f) * xn);
    float g  = __expf((16.f / 15.f) * xn);
    float g2 = g * g, g4 = g2 * g2, g8 = g4 * g4;
    fp16x2 gg = __builtin_amdgcn_cvt_pkrtz(g2, g2);
    union { fp16x2 q[4]; half8 v8; } u0, u1;
    u0.q[0] = __builtin_amdgcn_cvt_pkrtz(Wv, Wv * g);
    u0.q[1] = u0.q[0] * gg;
    u0.q[2] = u0.q[1] * gg;
    u0.q[3] = u0.q[2] * gg;
    float W8 = Wv * g8;
    u1.q[0] = __builtin_amdgcn_cvt_pkrtz(W8, W8 * g);
    u1.q[1] = u1.q[0] * gg;
    u1.q[2] = u1.q[1] * gg;
    u1.q[3] = u1.q[2] * gg;
    int ks0 = 2 * eh;
    *(half8*)&Asb[(size_t)bufi * 8192 + (size_t)(ks0 * 128 + erow) * 8]       = u0.v8;
    *(half8*)&Asb[(size_t)bufi * 8192 + (size_t)((ks0 + 1) * 128 + erow) * 8] = u1.v8;
  };

  // ---- prologue: DMA(0), DMA(1), expand(0); one-time vmcnt(0) drain ----
  float  x0  = xp[0];
  float2 sn0 = snp[0];
  gld16(gB, &Bsb[(size_t)tid * 8]);
  gld16(gB + (size_t)64 * K, &Bsb[(size_t)(tid + 512) * 8]);
  __builtin_amdgcn_sched_barrier(0);
  gld16(gB + 64, &Bsb[8192 + (size_t)tid * 8]);
  gld16(gB + 64 + (size_t)64 * K, &Bsb[8192 + (size_t)(tid + 512) * 8]);
  __builtin_amdgcn_sched_barrier(0);
  float  xv = xp[4];
  float2 sv = snp[4];
  expand_store(x0, sn0, 0);
  asm volatile("s_waitcnt vmcnt(0)" ::: "memory");
  asm volatile("s_waitcnt lgkmcnt(0)" ::: "memory");
  __builtin_amdgcn_s_barrier();
  __builtin_amdgcn_sched_barrier(0);

  // ---- main loop: raw barrier per step, vmcnt never drained; role-ordered by ksw ----
  int bcur = 0;
  for (int k = 0; k < steps; k++) {
    const int abuf = k & 1;
    const bool more  = (k + 1 < steps);
    const bool more2 = (k + 2 < steps);
    const int b2 = (bcur == 0) ? 2 : bcur - 1;
    if (more2) {
      gld16(gB + (size_t)(k + 2) * 64, &Bsb[(size_t)b2 * 8192 + (size_t)tid * 8]);
      gld16(gB + (size_t)(k + 2) * 64 + (size_t)64 * K,
            &Bsb[(size_t)b2 * 8192 + (size_t)(tid + 512) * 8]);
      __builtin_amdgcn_sched_barrier(0);
    }
    half8 af[2][2], bf[2][2];                    // [kc][mi] / [kc][ni]
    auto read_frags = [&]() {
#pragma unroll
      for (int kc = 0; kc < 2; kc++) {
        int kseg = ksw * 4 + kc * 2 + khalf;
#pragma unroll
        for (int mi = 0; mi < 2; mi++) {
          int arow = wm * 64 + mi * 32 + lane31;
          af[kc][mi] = *(const half8*)&Asb[(size_t)abuf * 8192 + (size_t)(kseg * 128 + arow) * 8];
        }
#pragma unroll
        for (int ni = 0; ni < 2; ni++) {
          int brow = wn * 64 + ni * 32 + lane31;
          int bchunk = brow * 8 + (kseg ^ ((brow >> 1) & 7));
          bf[kc][ni] = *(const half8*)&Bsb[(size_t)bcur * 8192 + (size_t)bchunk * 8];
        }
      }
    };
    auto do_expand = [&]() {
      if (more) {
        expand_store(xv, sv, abuf ^ 1);
        if (more2) {
          xv = xp[4 * (k + 2)];
          sv = snp[4 * (k + 2)];
        }
      }
    };
    if (ksw == 0) {
      // [frags -> MFMA kc0 -> expand -> MFMA kc1]
      read_frags();
      __builtin_amdgcn_s_setprio(1);
#pragma unroll
      for (int mi = 0; mi < 2; mi++)
#pragma unroll
        for (int ni = 0; ni < 2; ni++)
          acc[mi][ni] = __builtin_amdgcn_mfma_f32_32x32x16_f16(af[0][mi], bf[0][ni], acc[mi][ni], 0, 0, 0);
      __builtin_amdgcn_s_setprio(0);
      do_expand();
      __builtin_amdgcn_s_setprio(1);
#pragma unroll
      for (int mi = 0; mi < 2; mi++)
#pragma unroll
        for (int ni = 0; ni < 2; ni++)
          acc[mi][ni] = __builtin_amdgcn_mfma_f32_32x32x16_f16(af[1][mi], bf[1][ni], acc[mi][ni], 0, 0, 0);
      __builtin_amdgcn_s_setprio(0);
    } else {
      // [expand -> frags -> MFMA all]: VALU first while ksw=0 waves hit LDS/MFMA
      do_expand();
      read_frags();
      __builtin_amdgcn_s_setprio(1);
#pragma unroll
      for (int kc = 0; kc < 2; kc++)
#pragma unroll
        for (int mi = 0; mi < 2; mi++)
#pragma unroll
          for (int ni = 0; ni < 2; ni++)
            acc[mi][ni] = __builtin_amdgcn_mfma_f32_32x32x16_f16(af[kc][mi], bf[kc][ni], acc[mi][ni], 0, 0, 0);
      __builtin_amdgcn_s_setprio(0);
    }
    asm volatile("s_waitcnt lgkmcnt(0)" ::: "memory");
    __builtin_amdgcn_s_barrier();
    __builtin_amdgcn_sched_barrier(0);
    bcur = (bcur == 2) ? 0 : bcur + 1;
  }

  // ---- k-split merge: ks=1 waves dump acc into the (dead) LDS arena; ks=0 adds ----
  float* MB = reinterpret_cast<float*>(LDSB);        // [0,64K): 4 tiles x 16 KB
  const int p = wm * 2 + wn;                         // spatial tile id 0..3
  asm volatile("s_waitcnt vmcnt(0)" ::: "memory");   // safety: all DMA landed (one-time)
  if (ksw == 1) {
    float* dst = MB + (size_t)p * 4096;
#pragma unroll
    for (int mi = 0; mi < 2; mi++)
#pragma unroll
      for (int ni = 0; ni < 2; ni++)
#pragma unroll
        for (int r = 0; r < 16; r++)
          dst[((mi * 2 + ni) * 16 + r) * 64 + lane] = acc[mi][ni][r];
  }
  asm volatile("s_waitcnt lgkmcnt(0)" ::: "memory");
  __builtin_amdgcn_s_barrier();
  __builtin_amdgcn_sched_barrier(0);

  // ---- epilogue on ks=0 waves: merge + tanh + store + column partial sums ----
  // C/D layout (32x32): col = lane&31, row = (r&3) + 8*(r>>2) + 4*khalf
  float* Rs1 = MB + 16384;                           // [64K,66K): [2][128] + [2][128]
  float* Rs2 = Rs1 + 256;
  if (ksw == 0) {
    const float* src = MB + (size_t)p * 4096;
    float s1[2] = {0.f, 0.f}, s2v[2] = {0.f, 0.f};
#pragma unroll
    for (int mi = 0; mi < 2; mi++) {
#pragma unroll
      for (int ni = 0; ni < 2; ni++) {
        int gcol = col0 + wn * 64 + ni * 32 + lane31;
#pragma unroll
        for (int r = 0; r < 16; r++) {
          float other = src[((mi * 2 + ni) * 16 + r) * 64 + lane];
          int row = (r & 3) + 8 * (r >> 2) + 4 * khalf;
          int grow = row0 + wm * 64 + mi * 32 + row;
          float v = fast_tanh(acc[mi][ni][r] + other);
          Hout[(size_t)grow * H_DIM + gcol] = v;
          s1[ni] += v; s2v[ni] += v * v;
        }
      }
    }
    // lanes l and l+32 share gcol and cover complementary rows -> one xor-32 reduce
#pragma unroll
    for (int ni = 0; ni < 2; ni++) {
      s1[ni]  += __shfl_xor(s1[ni], 32);
      s2v[ni] += __shfl_xor(s2v[ni], 32);
    }
    if (khalf == 0) {
#pragma unroll
      for (int ni = 0; ni < 2; ni++) {
        Rs1[wm * 128 + wn * 64 + ni * 32 + lane31] = s1[ni];
        Rs2[wm * 128 + wn * 64 + ni * 32 + lane31] = s2v[ni];
      }
    }
  }
  asm volatile("s_waitcnt lgkmcnt(0)" ::: "memory");    // avoid draining Hout stores
  __builtin_amdgcn_s_barrier();
  __builtin_amdgcn_sched_barrier(0);
  if (tid < 128) {
    dev_store(&psum [(size_t)blockIdx.x * H_DIM + col0 + tid], Rs1[tid] + Rs1[128 + tid]);
    dev_store(&psum2[(size_t)blockIdx.x * H_DIM + col0 + tid], Rs2[tid] + Rs2[128 + tid]);
  }

  // ---- arrive (relaxed; sc1 stores already device-visible) + last-block H-stats ----
  int* lastf = reinterpret_cast<int*>(MB + 16896);   // LDS dead slot
  __syncthreads();                                   // all waves' stores drained (vmcnt 0)
  if (tid == 0) {
    unsigned old = __hip_atomic_fetch_add(cnt, 1u, __ATOMIC_RELAXED, __HIP_MEMORY_SCOPE_AGENT);
    *lastf = (old == gridDim.x * gridDim.y - 1) ? 1 : 0;
  }
  __syncthreads();
  if (*lastf) {
    double s = 0.0, s2 = 0.0;
    for (int g = 0; g < 128; g++) {
      s  += dev_load(&psum [(size_t)g * H_DIM + tid]);
      s2 += dev_load(&psum2[(size_t)g * H_DIM + tid]);
    }
    double mean = s / B_ROWS;
    double var  = (s2 - s * s / B_ROWS) / (B_ROWS - 1);   // ddof=1
    if (var < 0.0) var = 0.0;
    float iv = 1.0f / ((float)sqrt(var) + 1e-6f);
    snpk_out[tid] = make_float2(iv, -(float)mean * iv);
  }
}

// ---------------- layer 3 (out dim 1) + skip, fp32, normalize fused ----------------
__global__ __launch_bounds__(256) void layer3_k(const float* __restrict__ H2,
                                                const float2* __restrict__ snpk,
                                                const float* __restrict__ C3,
                                                const float* __restrict__ X,
                                                const float* __restrict__ SW,
                                                const float* __restrict__ SB,
                                                float* __restrict__ OUT) {
  int w = threadIdx.x >> 6, lane = threadIdx.x & 63;
  float Kn[NB];
#pragma unroll
  for (int n = 0; n < NB; n++) {
    float c = -2.f + (float)n * (4.f / 15.f);
    Kn[n] = __expf(-2.f * c * c);
  }
  float sb0 = SB[0];
  int row_base = blockIdx.x * 16 + w * 4;
  for (int r = 0; r < 4; r++) {
    int row = row_base + r;
    float s = 0.f;
#pragma unroll
    for (int j = 0; j < 8; j++) {
      int i = lane + 64 * j;
      float hv = H2[(size_t)row * H_DIM + i];
      float2 sn = snpk[i];
      float xn = fminf(fmaxf(fmaf(hv, sn.x, sn.y), -3.f), 3.f);
      float Wf = __expf(fmaf(-2.f, xn, -8.f) * xn);
      float gf = __expf((16.f / 15.f) * xn);
      const floatx4* cp = (const floatx4*)(C3 + (size_t)i * NB);
      floatx4 c0 = cp[0], c1 = cp[1], c2 = cp[2], c3 = cp[3];
      float p = Wf;
#pragma unroll
      for (int n = 0; n < 4; n++) { s += p * Kn[n]      * c0[n]; p *= gf; }
#pragma unroll
      for (int n = 0; n < 4; n++) { s += p * Kn[n + 4]  * c1[n]; p *= gf; }
#pragma unroll
      for (int n = 0; n < 4; n++) { s += p * Kn[n + 8]  * c2[n]; p *= gf; }
#pragma unroll
      for (int n = 0; n < 4; n++) { s += p * Kn[n + 12] * c3[n]; p *= gf; }
    }
#pragma unroll
    for (int j = 0; j < 4; j++) {
      int i = lane + 64 * j;
      s += X[(size_t)row * IN_DIM + i] * SW[i];
    }
#pragma unroll
    for (int off = 32; off > 0; off >>= 1) s += __shfl_down(s, off);
    if (lane == 0) OUT[row] = s + sb0;
  }
}

// ---------------- launcher ----------------
extern "C" void kernel_launch(void* const* d_in, const int* in_sizes, int n_in,
                              void* d_out, int out_size, void* d_ws, size_t ws_size,
                              hipStream_t stream) {
  const float* x  = (const float*)d_in[0];   // [16384, 256]
  const float* c1 = (const float*)d_in[1];   // [512, 256, 16]
  const float* c2 = (const float*)d_in[2];   // [512, 512, 16]
  const float* c3 = (const float*)d_in[3];   // [1, 512, 16]
  const float* sw = (const float*)d_in[4];   // [1, 256]
  const float* sb = (const float*)d_in[5];   // [1]
  float* out = (float*)d_out;

  const int B = B_ROWS, IN = IN_DIM, H = H_DIM;

  char* ws = (char*)d_ws;
  size_t off = 0;
  auto alloc = [&](size_t bytes) -> void* {
    void* p = ws + off;
    off += (bytes + 255) & ~(size_t)255;
    return p;
  };
  unsigned* cnts = (unsigned*)alloc(256);                     // 3 arrive counters
  _Float16* C1h = (_Float16*)alloc((size_t)H * IN * NB * 2);  //  4 MB
  _Float16* C2h = (_Float16*)alloc((size_t)H * H  * NB * 2);  //  8 MB
  float* H1 = (float*)alloc((size_t)B * H * 4);               // 32 MB
  float* H2 = (float*)alloc((size_t)B * H * 4);               // 32 MB
  float* ps  = (float*)alloc(128 * 512 * 4);                  // shared partials buffer
  float* ps2 = (float*)alloc(128 * 512 * 4);
  float2* snpkX = (float2*)alloc(512 * 8);                    // distinct per producer
  float2* snpkA = (float2*)alloc(512 * 8);
  float2* snpkB = (float2*)alloc(512 * 8);

  // zero arrive counters (stream-ordered, graph-capturable)
  hipMemsetAsync(cnts, 0, 256, stream);

  // ---- prep: x-stats partials + coeff cvt + last-block x-stats finalize ----
  prep_k<<<128 + 1024, 256, 0, stream>>>(c1, C1h, (size_t)H * IN * NB / 4,
                                         c2, C2h, (size_t)H * H * NB / 4,
                                         x, ps, ps2, cnts + 0, snpkX);

  // ---- layer 1 (C=256, K=4096); last-block H1-stats finalize ----
  kan_gemm_fused<<<dim3(B / 128, 4), 512, 0, stream>>>(x, snpkX, C1h, H1, ps, ps2, IN,
                                                       cnts + 16, snpkA);

  // ---- layer 2 (C=512, K=8192); last-block H2-stats finalize ----
  kan_gemm_fused<<<dim3(B / 128, 4), 512, 0, stream>>>(H1, snpkA, C2h, H2, ps, ps2, H,
                                                       cnts + 32, snpkB);

  // ---- layer 3 + skip ----
  layer3_k<<<B / 16, 256, 0, stream>>>(H2, snpkB, c3, x, sw, sb, out);
}

// Round 18
// 393.172 us; speedup vs baseline: 1.5056x; 1.1148x over previous
//
#include <hip/hip_runtime.h>
#include <cstdint>
#include <cstddef>

// ---------------- types ----------------
typedef __attribute__((ext_vector_type(8))) _Float16 half8;   // MFMA f16 A/B frag (4 VGPRs)
typedef __attribute__((ext_vector_type(4))) _Float16 half4;
typedef __attribute__((ext_vector_type(2))) __fp16   fp16x2;  // cvt_pkrtz result type
typedef __attribute__((ext_vector_type(4))) float    floatx4; // MFMA C/D frag

static constexpr int B_ROWS = 16384;
static constexpr int IN_DIM = 256;
static constexpr int H_DIM  = 512;
static constexpr int NB     = 16;

__device__ __forceinline__ float fast_tanh(float x) {
  float ax = fabsf(x);
  float e  = __expf(2.0f * ax);             // e >= 1, inf-safe
  float t  = 1.0f - 2.0f / (e + 1.0f);
  return copysignf(t, x);
}

// async global->LDS, 16B per lane; LDS dest must be wave-uniform base + lane*16
__device__ __forceinline__ void gld16(const void* g, void* l) {
  __builtin_amdgcn_global_load_lds(
      (const __attribute__((address_space(1))) unsigned int*)g,
      (__attribute__((address_space(3))) unsigned int*)l, 16, 0, 0);
}

// device-scope (coherent-point) relaxed store/load: no L2-dirty state, no fences needed.
__device__ __forceinline__ void dev_store(float* p, float v) {
  __hip_atomic_store(p, v, __ATOMIC_RELAXED, __HIP_MEMORY_SCOPE_AGENT);
}
__device__ __forceinline__ float dev_load(const float* p) {
  return __hip_atomic_load(p, __ATOMIC_RELAXED, __HIP_MEMORY_SCOPE_AGENT);
}

// ---------------- prep: x column-stats partials + coeff cvt + last-block x-stats finalize ----
// R21 tail (R15-measured best): sc1-store partials + RELAXED arrive (no wbl2) +
// last-block finalize via device-scope loads.
__global__ __launch_bounds__(256) void prep_k(const float* __restrict__ c1, _Float16* __restrict__ d1, size_t n41,
                                              const float* __restrict__ c2, _Float16* __restrict__ d2, size_t n42,
                                              const float* __restrict__ X,
                                              float* __restrict__ ps, float* __restrict__ ps2,
                                              unsigned* __restrict__ cnt,
                                              float2* __restrict__ snpk) {
  const int bx = blockIdx.x;
  __shared__ float Ls[256], Ls2[256];
  __shared__ int lastf;
  if (bx < 128) {
    // ---- stats on X: cols=256 (4 col-groups of 64), 32 row-segs of 512 ----
    int c     = (bx & 3) * 64 + (threadIdx.x & 63);
    int chunk = threadIdx.x >> 6;
    int seg   = bx >> 2;
    int r0    = seg * 512;
    double s = 0.0, s2 = 0.0;
    for (int r = r0 + chunk; r < r0 + 512; r += 4) {
      float v = X[(size_t)r * IN_DIM + c];
      s += v; s2 += (double)v * (double)v;
    }
    Ls[threadIdx.x] = (float)s; Ls2[threadIdx.x] = (float)s2;
    __syncthreads();
    if (chunk == 0) {
      int cl = threadIdx.x;
      float a  = Ls[cl]  + Ls[cl + 64]  + Ls[cl + 128]  + Ls[cl + 192];
      float b  = Ls2[cl] + Ls2[cl + 64] + Ls2[cl + 128] + Ls2[cl + 192];
      dev_store(&ps [(size_t)seg * IN_DIM + c], a);
      dev_store(&ps2[(size_t)seg * IN_DIM + c], b);
    }
  } else {
    // ---- coeff conversion, grid-stride over remaining blocks ----
    size_t tot = n41 + n42;
    int nb_blocks = gridDim.x - 128;
    for (size_t i = (size_t)(bx - 128) * 256 + threadIdx.x; i < tot;
         i += (size_t)nb_blocks * 256) {
      const float4* sp; half4* dp; size_t j;
      if (i < n41) { sp = (const float4*)c1; dp = (half4*)d1; j = i; }
      else         { sp = (const float4*)c2; dp = (half4*)d2; j = i - n41; }
      float4 v = sp[j];
      int nb = (int)((j << 2) & 15);
      half4 r;
      float e0 = -2.f + (float)(nb + 0) * (4.f / 15.f);
      float e1 = -2.f + (float)(nb + 1) * (4.f / 15.f);
      float e2 = -2.f + (float)(nb + 2) * (4.f / 15.f);
      float e3 = -2.f + (float)(nb + 3) * (4.f / 15.f);
      r[0] = (_Float16)(v.x * __expf(-2.f * e0 * e0));
      r[1] = (_Float16)(v.y * __expf(-2.f * e1 * e1));
      r[2] = (_Float16)(v.z * __expf(-2.f * e2 * e2));
      r[3] = (_Float16)(v.w * __expf(-2.f * e3 * e3));
      dp[j] = r;
    }
  }
  // ---- arrive (relaxed; stores already device-visible) + last-block x-stats finalize ----
  __syncthreads();
  if (threadIdx.x == 0) {
    unsigned old = __hip_atomic_fetch_add(cnt, 1u, __ATOMIC_RELAXED, __HIP_MEMORY_SCOPE_AGENT);
    lastf = (old == gridDim.x - 1) ? 1 : 0;
  }
  __syncthreads();
  if (lastf) {
    int c = threadIdx.x;                    // 256 threads, 256 cols
    double s = 0.0, s2 = 0.0;
    for (int g = 0; g < 32; g++) {
      s  += dev_load(&ps [(size_t)g * IN_DIM + c]);
      s2 += dev_load(&ps2[(size_t)g * IN_DIM + c]);
    }
    double mean = s / B_ROWS;
    double var  = (s2 - s * s / B_ROWS) / (B_ROWS - 1);   // ddof=1
    if (var < 0.0) var = 0.0;
    float iv = 1.0f / ((float)sqrt(var) + 1e-6f);
    snpk[c] = make_float2(iv, -(float)mean * iv);
  }
}

// ---------------- fused normalize+expand+GEMM+tanh + col-partials + last-block stats ----
// H[b, o] = tanh( sum_k basis(xn[b, k/16])_[k%16] * Cb[o, k] ),  K = C*16
// 128x128 tile, BK=64, 512 threads, grid (128,4), 2 blocks/CU. Main loop = R10
// (best measured). 16x16x32 MFMA is load-bearing for ILP (R17: 32x32x16 regressed
// -13% — fewer, longer MFMAs serialize on the acc chain). k-split wave grid
// (8 waves = 2m x 2n x 2k, kq=ksw*4+quad, 8 LDS reads/wave/step), role-ordered wave
// groups (ksw=1 expand-first), 80 KB LDS arena, DMA tri-buffer + counted vmcnt
// (never drained in-loop), erow=tid&127 A-write banking (conflicts=0), packed f16
// expansion, lgkm-only raw barriers, LDS k-split merge. R21 tail: sc1-store
// partials + RELAXED arrive (no wbl2) + last-block stats via device-scope loads.
__global__ __launch_bounds__(512, 4) void kan_gemm_fused(const float* __restrict__ X,   // [B, C]
                                                         const float2* __restrict__ snpk, // [C] in
                                                         const _Float16* __restrict__ Bm, // [512, C*16]
                                                         float* __restrict__ Hout,        // [B, 512]
                                                         float* __restrict__ psum,        // [128, 512]
                                                         float* __restrict__ psum2,       // [128, 512]
                                                         int C,
                                                         unsigned* __restrict__ cnt,
                                                         float2* __restrict__ snpk_out) { // [512] out (distinct)
  const int K = C << 4;
  const int steps = K >> 6;                 // BK = 64
  __shared__ __align__(16) unsigned char LDSB[81920];
  _Float16* const Asb = reinterpret_cast<_Float16*>(LDSB);           // 2 x 8192 halfs
  _Float16* const Bsb = reinterpret_cast<_Float16*>(LDSB + 32768);   // 3 x 8192 halfs
  const int tid  = threadIdx.x;
  const int w = tid >> 6, lane = tid & 63;
  const int wm = w & 1, wn = (w >> 1) & 1, ksw = w >> 2;  // 2x2 spatial, 2-way k-split
  const int lrow = lane & 15, quad = lane >> 4;
  const int row0 = blockIdx.x * 128;
  const int col0 = blockIdx.y * 128;
  const int kq = ksw * 4 + quad;            // this lane's kseg within BK=64

  const int s_row = tid >> 3;               // 0..63
  const int s_sl  = tid & 7;
  const int s_seg = s_sl ^ ((s_row >> 1) & 7);
  const _Float16* gB = Bm + (size_t)(col0 + s_row) * K + s_seg * 8;

  const int erow = tid & 127;
  const int eh   = tid >> 7;
  const float*  xp  = X    + (size_t)(row0 + erow) * C + eh;  // step k: xp[4k]
  const float2* snp = snpk + eh;                              // step k: snp[4k]

  floatx4 acc[4][4] = {};

  auto expand_store = [&](float xr, float2 sn, int bufi) {
    float xn = fminf(fmaxf(fmaf(xr, sn.x, sn.y), -3.f), 3.f);
    float Wv = __expf(fmaf(-2.f, xn, -8.f) * xn);
    float g  = __expf((16.f / 15.f) * xn);
    float g2 = g * g, g4 = g2 * g2, g8 = g4 * g4;
    fp16x2 gg = __builtin_amdgcn_cvt_pkrtz(g2, g2);
    union { fp16x2 q[4]; half8 v8; } u0, u1;
    u0.q[0] = __builtin_amdgcn_cvt_pkrtz(Wv, Wv * g);
    u0.q[1] = u0.q[0] * gg;
    u0.q[2] = u0.q[1] * gg;
    u0.q[3] = u0.q[2] * gg;
    float W8 = Wv * g8;
    u1.q[0] = __builtin_amdgcn_cvt_pkrtz(W8, W8 * g);
    u1.q[1] = u1.q[0] * gg;
    u1.q[2] = u1.q[1] * gg;
    u1.q[3] = u1.q[2] * gg;
    int ks0 = 2 * eh;
    *(half8*)&Asb[(size_t)bufi * 8192 + (size_t)(ks0 * 128 + erow) * 8]       = u0.v8;
    *(half8*)&Asb[(size_t)bufi * 8192 + (size_t)((ks0 + 1) * 128 + erow) * 8] = u1.v8;
  };

  // ---- prologue: DMA(0), DMA(1), expand(0); one-time vmcnt(0) drain ----
  float  x0  = xp[0];
  float2 sn0 = snp[0];
  gld16(gB, &Bsb[(size_t)tid * 8]);
  gld16(gB + (size_t)64 * K, &Bsb[(size_t)(tid + 512) * 8]);
  __builtin_amdgcn_sched_barrier(0);
  gld16(gB + 64, &Bsb[8192 + (size_t)tid * 8]);
  gld16(gB + 64 + (size_t)64 * K, &Bsb[8192 + (size_t)(tid + 512) * 8]);
  __builtin_amdgcn_sched_barrier(0);
  float  xv = xp[4];
  float2 sv = snp[4];
  expand_store(x0, sn0, 0);
  asm volatile("s_waitcnt vmcnt(0)" ::: "memory");
  asm volatile("s_waitcnt lgkmcnt(0)" ::: "memory");
  __builtin_amdgcn_s_barrier();
  __builtin_amdgcn_sched_barrier(0);

  // ---- main loop: raw barrier per step, vmcnt never drained; role-ordered by ksw ----
  int bcur = 0;
  for (int k = 0; k < steps; k++) {
    const int abuf = k & 1;
    const bool more  = (k + 1 < steps);
    const bool more2 = (k + 2 < steps);
    const int b2 = (bcur == 0) ? 2 : bcur - 1;
    if (more2) {
      gld16(gB + (size_t)(k + 2) * 64, &Bsb[(size_t)b2 * 8192 + (size_t)tid * 8]);
      gld16(gB + (size_t)(k + 2) * 64 + (size_t)64 * K,
            &Bsb[(size_t)b2 * 8192 + (size_t)(tid + 512) * 8]);
      __builtin_amdgcn_sched_barrier(0);
    }
    half8 af[4], bf[4];
    auto read_frags = [&]() {
#pragma unroll
      for (int t = 0; t < 4; t++) {
        int arow = wm * 64 + t * 16 + lrow;
        af[t] = *(const half8*)&Asb[(size_t)abuf * 8192 + (size_t)(kq * 128 + arow) * 8];
      }
#pragma unroll
      for (int t = 0; t < 4; t++) {
        int brow = wn * 64 + t * 16 + lrow;
        int bchunk = brow * 8 + (kq ^ ((brow >> 1) & 7));
        bf[t] = *(const half8*)&Bsb[(size_t)bcur * 8192 + (size_t)bchunk * 8];
      }
    };
    auto do_expand = [&]() {
      if (more) {
        expand_store(xv, sv, abuf ^ 1);
        if (more2) {
          xv = xp[4 * (k + 2)];
          sv = snp[4 * (k + 2)];
        }
      }
    };
    if (ksw == 0) {
      read_frags();
      __builtin_amdgcn_s_setprio(1);
#pragma unroll
      for (int tm = 0; tm < 2; tm++)
#pragma unroll
        for (int tn = 0; tn < 4; tn++)
          acc[tm][tn] = __builtin_amdgcn_mfma_f32_16x16x32_f16(af[tm], bf[tn], acc[tm][tn], 0, 0, 0);
      __builtin_amdgcn_s_setprio(0);
      do_expand();
      __builtin_amdgcn_s_setprio(1);
#pragma unroll
      for (int tm = 2; tm < 4; tm++)
#pragma unroll
        for (int tn = 0; tn < 4; tn++)
          acc[tm][tn] = __builtin_amdgcn_mfma_f32_16x16x32_f16(af[tm], bf[tn], acc[tm][tn], 0, 0, 0);
      __builtin_amdgcn_s_setprio(0);
    } else {
      do_expand();
      read_frags();
      __builtin_amdgcn_s_setprio(1);
#pragma unroll
      for (int tm = 0; tm < 4; tm++)
#pragma unroll
        for (int tn = 0; tn < 4; tn++)
          acc[tm][tn] = __builtin_amdgcn_mfma_f32_16x16x32_f16(af[tm], bf[tn], acc[tm][tn], 0, 0, 0);
      __builtin_amdgcn_s_setprio(0);
    }
    asm volatile("s_waitcnt lgkmcnt(0)" ::: "memory");
    __builtin_amdgcn_s_barrier();
    __builtin_amdgcn_sched_barrier(0);
    bcur = (bcur == 2) ? 0 : bcur + 1;
  }

  // ---- k-split merge: ks=1 waves dump acc into the (dead) LDS arena; ks=0 adds ----
  float* MB = reinterpret_cast<float*>(LDSB);
  const int p = wm * 2 + wn;
  asm volatile("s_waitcnt vmcnt(0)" ::: "memory");
  if (ksw == 1) {
    float* dst = MB + (size_t)p * 4096;
#pragma unroll
    for (int tm = 0; tm < 4; tm++)
#pragma unroll
      for (int tn = 0; tn < 4; tn++)
        *(floatx4*)&dst[((tm * 4 + tn) * 64 + lane) * 4] = acc[tm][tn];
  }
  asm volatile("s_waitcnt lgkmcnt(0)" ::: "memory");
  __builtin_amdgcn_s_barrier();
  __builtin_amdgcn_sched_barrier(0);

  float* Rs1 = MB + 16384;
  float* Rs2 = Rs1 + 256;
  if (ksw == 0) {
    const float* src = MB + (size_t)p * 4096;
    float s1[4] = {0.f, 0.f, 0.f, 0.f}, s2v[4] = {0.f, 0.f, 0.f, 0.f};
#pragma unroll
    for (int tm = 0; tm < 4; tm++) {
#pragma unroll
      for (int tn = 0; tn < 4; tn++) {
        floatx4 other = *(const floatx4*)&src[((tm * 4 + tn) * 64 + lane) * 4];
        int gcol = col0 + wn * 64 + tn * 16 + lrow;
#pragma unroll
        for (int r = 0; r < 4; r++) {
          int grow = row0 + wm * 64 + tm * 16 + quad * 4 + r;
          float v = fast_tanh(acc[tm][tn][r] + other[r]);
          Hout[(size_t)grow * H_DIM + gcol] = v;
          s1[tn] += v; s2v[tn] += v * v;
        }
      }
    }
#pragma unroll
    for (int tn = 0; tn < 4; tn++) {
      s1[tn]  += __shfl_xor(s1[tn], 16);  s1[tn]  += __shfl_xor(s1[tn], 32);
      s2v[tn] += __shfl_xor(s2v[tn], 16); s2v[tn] += __shfl_xor(s2v[tn], 32);
    }
    if (quad == 0) {
#pragma unroll
      for (int tn = 0; tn < 4; tn++) {
        Rs1[wm * 128 + wn * 64 + tn * 16 + lrow] = s1[tn];
        Rs2[wm * 128 + wn * 64 + tn * 16 + lrow] = s2v[tn];
      }
    }
  }
  asm volatile("s_waitcnt lgkmcnt(0)" ::: "memory");
  __builtin_amdgcn_s_barrier();
  __builtin_amdgcn_sched_barrier(0);
  if (tid < 128) {
    dev_store(&psum [(size_t)blockIdx.x * H_DIM + col0 + tid], Rs1[tid] + Rs1[128 + tid]);
    dev_store(&psum2[(size_t)blockIdx.x * H_DIM + col0 + tid], Rs2[tid] + Rs2[128 + tid]);
  }

  // ---- arrive (relaxed; sc1 stores already device-visible) + last-block H-stats ----
  int* lastf = reinterpret_cast<int*>(MB + 16896);   // LDS dead slot
  __syncthreads();                                   // all waves' stores drained (vmcnt 0)
  if (tid == 0) {
    unsigned old = __hip_atomic_fetch_add(cnt, 1u, __ATOMIC_RELAXED, __HIP_MEMORY_SCOPE_AGENT);
    *lastf = (old == gridDim.x * gridDim.y - 1) ? 1 : 0;
  }
  __syncthreads();
  if (*lastf) {
    // thread c computes column c (512 threads, 512 cols, 128 segs ascending, f64)
    double s = 0.0, s2 = 0.0;
    for (int g = 0; g < 128; g++) {
      s  += dev_load(&psum [(size_t)g * H_DIM + tid]);
      s2 += dev_load(&psum2[(size_t)g * H_DIM + tid]);
    }
    double mean = s / B_ROWS;
    double var  = (s2 - s * s / B_ROWS) / (B_ROWS - 1);   // ddof=1
    if (var < 0.0) var = 0.0;
    float iv = 1.0f / ((float)sqrt(var) + 1e-6f);
    snpk_out[tid] = make_float2(iv, -(float)mean * iv);
  }
}

// ---------------- layer 3 (out dim 1) + skip, fp32, normalize fused ----------------
__global__ __launch_bounds__(256) void layer3_k(const float* __restrict__ H2,
                                                const float2* __restrict__ snpk,
                                                const float* __restrict__ C3,
                                                const float* __restrict__ X,
                                                const float* __restrict__ SW,
                                                const float* __restrict__ SB,
                                                float* __restrict__ OUT) {
  int w = threadIdx.x >> 6, lane = threadIdx.x & 63;
  float Kn[NB];
#pragma unroll
  for (int n = 0; n < NB; n++) {
    float c = -2.f + (float)n * (4.f / 15.f);
    Kn[n] = __expf(-2.f * c * c);
  }
  float sb0 = SB[0];
  int row_base = blockIdx.x * 16 + w * 4;
  for (int r = 0; r < 4; r++) {
    int row = row_base + r;
    float s = 0.f;
#pragma unroll
    for (int j = 0; j < 8; j++) {
      int i = lane + 64 * j;
      float hv = H2[(size_t)row * H_DIM + i];
      float2 sn = snpk[i];
      float xn = fminf(fmaxf(fmaf(hv, sn.x, sn.y), -3.f), 3.f);
      float Wf = __expf(fmaf(-2.f, xn, -8.f) * xn);
      float gf = __expf((16.f / 15.f) * xn);
      const floatx4* cp = (const floatx4*)(C3 + (size_t)i * NB);
      floatx4 c0 = cp[0], c1 = cp[1], c2 = cp[2], c3 = cp[3];
      float p = Wf;
#pragma unroll
      for (int n = 0; n < 4; n++) { s += p * Kn[n]      * c0[n]; p *= gf; }
#pragma unroll
      for (int n = 0; n < 4; n++) { s += p * Kn[n + 4]  * c1[n]; p *= gf; }
#pragma unroll
      for (int n = 0; n < 4; n++) { s += p * Kn[n + 8]  * c2[n]; p *= gf; }
#pragma unroll
      for (int n = 0; n < 4; n++) { s += p * Kn[n + 12] * c3[n]; p *= gf; }
    }
#pragma unroll
    for (int j = 0; j < 4; j++) {
      int i = lane + 64 * j;
      s += X[(size_t)row * IN_DIM + i] * SW[i];
    }
#pragma unroll
    for (int off = 32; off > 0; off >>= 1) s += __shfl_down(s, off);
    if (lane == 0) OUT[row] = s + sb0;
  }
}

// ---------------- launcher ----------------
extern "C" void kernel_launch(void* const* d_in, const int* in_sizes, int n_in,
                              void* d_out, int out_size, void* d_ws, size_t ws_size,
                              hipStream_t stream) {
  const float* x  = (const float*)d_in[0];   // [16384, 256]
  const float* c1 = (const float*)d_in[1];   // [512, 256, 16]
  const float* c2 = (const float*)d_in[2];   // [512, 512, 16]
  const float* c3 = (const float*)d_in[3];   // [1, 512, 16]
  const float* sw = (const float*)d_in[4];   // [1, 256]
  const float* sb = (const float*)d_in[5];   // [1]
  float* out = (float*)d_out;

  const int B = B_ROWS, IN = IN_DIM, H = H_DIM;

  char* ws = (char*)d_ws;
  size_t off = 0;
  auto alloc = [&](size_t bytes) -> void* {
    void* p = ws + off;
    off += (bytes + 255) & ~(size_t)255;
    return p;
  };
  unsigned* cnts = (unsigned*)alloc(256);                     // 3 arrive counters
  _Float16* C1h = (_Float16*)alloc((size_t)H * IN * NB * 2);  //  4 MB
  _Float16* C2h = (_Float16*)alloc((size_t)H * H  * NB * 2);  //  8 MB
  float* H1 = (float*)alloc((size_t)B * H * 4);               // 32 MB
  float* H2 = (float*)alloc((size_t)B * H * 4);               // 32 MB
  float* ps  = (float*)alloc(128 * 512 * 4);                  // shared partials buffer
  float* ps2 = (float*)alloc(128 * 512 * 4);
  float2* snpkX = (float2*)alloc(512 * 8);                    // distinct per producer (no aliasing UB)
  float2* snpkA = (float2*)alloc(512 * 8);
  float2* snpkB = (float2*)alloc(512 * 8);

  // zero arrive counters (stream-ordered, graph-capturable)
  hipMemsetAsync(cnts, 0, 256, stream);

  // ---- prep: x-stats partials + coeff cvt + last-block x-stats finalize ----
  prep_k<<<128 + 1024, 256, 0, stream>>>(c1, C1h, (size_t)H * IN * NB / 4,
                                         c2, C2h, (size_t)H * H * NB / 4,
                                         x, ps, ps2, cnts + 0, snpkX);

  // ---- layer 1 (C=256, K=4096); last-block H1-stats finalize ----
  kan_gemm_fused<<<dim3(B / 128, 4), 512, 0, stream>>>(x, snpkX, C1h, H1, ps, ps2, IN,
                                                       cnts + 16, snpkA);

  // ---- layer 2 (C=512, K=8192); last-block H2-stats finalize ----
  kan_gemm_fused<<<dim3(B / 128, 4), 512, 0, stream>>>(H1, snpkA, C2h, H2, ps, ps2, H,
                                                       cnts + 32, snpkB);

  // ---- layer 3 + skip ----
  layer3_k<<<B / 16, 256, 0, stream>>>(H2, snpkB, c3, x, sw, sb, out);
}